// Round 8
// baseline (327.693 us; speedup 1.0000x reference)
//
#include <hip/hip_runtime.h>
#include <hip/hip_bf16.h>

typedef __attribute__((ext_vector_type(8))) short short8;
typedef __attribute__((ext_vector_type(4))) float f32x4;

#define BN_EPS 1e-5f

// ---------- bf16 helpers (RNE) ----------
__device__ __forceinline__ float bf2f(unsigned short u) {
    unsigned int x = ((unsigned int)u) << 16;
    union { unsigned int i; float f; } c; c.i = x; return c.f;
}
__device__ __forceinline__ unsigned short f2bf(float f) {
    union { float f; unsigned int i; } c; c.f = f;
    unsigned int lsb = (c.i >> 16) & 1u;
    c.i += 0x7fffu + lsb;
    return (unsigned short)(c.i >> 16);
}
__device__ __forceinline__ unsigned long long pack4bf(float a, float b, float c, float d) {
    unsigned long long r = (unsigned long long)f2bf(a)
        | ((unsigned long long)f2bf(b) << 16)
        | ((unsigned long long)f2bf(c) << 32)
        | ((unsigned long long)f2bf(d) << 48);
    return r;
}

// ---------- async global->LDS 16B ----------
typedef const unsigned int __attribute__((address_space(1)))* gas_t;
typedef unsigned int __attribute__((address_space(3)))* las_t;
__device__ __forceinline__ void gload_lds16(const void* src, void* ldsdst) {
    __builtin_amdgcn_global_load_lds((gas_t)src, (las_t)ldsdst, 16, 0, 0);
}

// ---------- convert weights to bf16 ----------
__global__ __launch_bounds__(256) void k_convert(const float* __restrict__ W1,
        const float* __restrict__ W2, unsigned short* __restrict__ W1b,
        unsigned short* __restrict__ W2b) {
    int i = blockIdx.x * 256 + threadIdx.x;
    if (i < 256 * 384) W1b[i] = f2bf(W1[i]);
    if (i < 256 * 256) W2b[i] = f2bf(W2[i]);
}

// ---------- transpose p2 [b][256][1024] f32 -> p2t [b][1024][256] bf16 ----------
__global__ __launch_bounds__(256) void k_tr_p2(const float* __restrict__ p2,
        unsigned short* __restrict__ p2t) {
    __shared__ unsigned short btile[32][136];
    int b = blockIdx.y;
    int n0 = (blockIdx.x & 31) * 32;
    int c0 = (blockIdx.x >> 5) * 128;
    int t = threadIdx.x;
    const float* src = p2 + (size_t)b * 256 * 1024 + (size_t)c0 * 1024 + n0;
    int c4 = (t >> 3) * 4, n4 = (t & 7) * 4;
    f32x4 q0 = *(const f32x4*)&src[(size_t)(c4 + 0) * 1024 + n4];
    f32x4 q1 = *(const f32x4*)&src[(size_t)(c4 + 1) * 1024 + n4];
    f32x4 q2 = *(const f32x4*)&src[(size_t)(c4 + 2) * 1024 + n4];
    f32x4 q3 = *(const f32x4*)&src[(size_t)(c4 + 3) * 1024 + n4];
    #pragma unroll
    for (int j = 0; j < 4; ++j) {
        *(unsigned long long*)&btile[n4 + j][c4] = pack4bf(q0[j], q1[j], q2[j], q3[j]);
    }
    __syncthreads();
    int nn = t >> 3, cs = (t & 7) * 16;
    short8 v0 = *(const short8*)&btile[nn][cs];
    short8 v1 = *(const short8*)&btile[nn][cs + 8];
    unsigned short* dst = p2t + ((size_t)b * 1024 + n0 + nn) * 256 + c0 + cs;
    *(short8*)dst = v0;
    *(short8*)(dst + 8) = v1;
}

// ---------- fused 3-NN + build: Xt[b*4096+n][384] = concat(points1^T, interp) ----------
__global__ __launch_bounds__(256) void k_knnbuild(const float* __restrict__ xyz1,
        const float* __restrict__ xyz2, const float* __restrict__ p1,
        const unsigned short* __restrict__ p2t, unsigned short* __restrict__ Xt) {
    __shared__ f32x4 cand[1024];          // (x, y, z, |p|^2)
    __shared__ float mkd[32][25];         // 24 partial dists per query (+pad)
    __shared__ int   mki[32][25];         // 24 partial indices per query (+pad)
    __shared__ unsigned short btile[32][136];
    __shared__ int sidx[32][3];
    __shared__ float sw[32][3];
    int b = blockIdx.y;
    int n0 = blockIdx.x * 32;
    int t = threadIdx.x;

    // issue p1 loads early: they complete under the VALU-bound scan
    const float* p1b = p1 + (size_t)b * 128 * 4096 + n0;
    int c4 = (t >> 3) * 4, n4 = (t & 7) * 4;
    f32x4 q0 = *(const f32x4*)&p1b[(size_t)(c4 + 0) * 4096 + n4];
    f32x4 q1 = *(const f32x4*)&p1b[(size_t)(c4 + 1) * 4096 + n4];
    f32x4 q2 = *(const f32x4*)&p1b[(size_t)(c4 + 2) * 4096 + n4];
    f32x4 q3 = *(const f32x4*)&p1b[(size_t)(c4 + 3) * 4096 + n4];

    const float* x2 = xyz2 + (size_t)b * 3072;
    for (int i = t; i < 1024; i += 256) {
        float x = x2[i], y = x2[1024 + i], z = x2[2048 + i];
        f32x4 v;
        v[0] = x; v[1] = y; v[2] = z; v[3] = x * x + y * y + z * z;
        cand[i] = v;
    }
    __syncthreads();

    // scan: 8 splits x 128 candidates, exact-f32 branchless top-3
    int q = t & 31, s = t >> 5;
    int n = n0 + q;
    const float* x1 = xyz1 + (size_t)b * 12288;
    float px = x1[n], py = x1[4096 + n], pz = x1[8192 + n];
    float s1 = px * px + py * py + pz * pz;
    float d0 = 1e30f, d1 = 1e30f, d2 = 1e30f;
    int i0 = 0, i1 = 0, i2 = 0;
    int j0 = s * 128;
    #pragma unroll 4
    for (int jj = 0; jj < 128; ++jj) {
        int j = j0 + jj;
        f32x4 v = cand[j];
        // exact same expression tree as the passing serial version:
        float dot = px * v[0] + py * v[1] + pz * v[2];
        float d = -2.0f * dot; d += s1; d += v[3];
        bool b0 = d < d0, b1 = d < d1, b2 = d < d2;
        d2 = b1 ? d1 : (b2 ? d : d2);
        i2 = b1 ? i1 : (b2 ? j : i2);
        d1 = b0 ? d0 : (b1 ? d : d1);
        i1 = b0 ? i0 : (b1 ? j : i1);
        d0 = b0 ? d : d0;
        i0 = b0 ? j : i0;
    }
    mkd[q][s * 3 + 0] = d0; mki[q][s * 3 + 0] = i0;
    mkd[q][s * 3 + 1] = d1; mki[q][s * 3 + 1] = i1;
    mkd[q][s * 3 + 2] = d2; mki[q][s * 3 + 2] = i2;

    // p1 transpose into LDS (loads issued at top are done by now)
    #pragma unroll
    for (int j = 0; j < 4; ++j) {
        *(unsigned long long*)&btile[n4 + j][c4] = pack4bf(q0[j], q1[j], q2[j], q3[j]);
    }
    __syncthreads();   // covers mkd/mki partials AND btile

    // merge 24 partials (t<32) in ascending split (=index) order;
    // strict < keeps the earlier (lower-index) entry on ties, matching top_k.
    if (t < 32) {
        float e0 = 1e30f, e1 = 1e30f, e2 = 1e30f;
        int a0 = 0, a1 = 0, a2 = 0;
        #pragma unroll
        for (int m = 0; m < 24; ++m) {
            float d = mkd[t][m]; int j = mki[t][m];
            bool b0 = d < e0, b1 = d < e1, b2 = d < e2;
            e2 = b1 ? e1 : (b2 ? d : e2);
            a2 = b1 ? a1 : (b2 ? j : a2);
            e1 = b0 ? e0 : (b1 ? d : e1);
            a1 = b0 ? a0 : (b1 ? j : a1);
            e0 = b0 ? d : e0;
            a0 = b0 ? j : a0;
        }
        float dd0 = fmaxf(e0, 1e-10f), dd1 = fmaxf(e1, 1e-10f), dd2 = fmaxf(e2, 1e-10f);
        float w0 = 1.f / dd0, w1 = 1.f / dd1, w2 = 1.f / dd2;
        float swt = w0 + w1 + w2; w0 /= swt; w1 /= swt; w2 /= swt;
        sidx[t][0] = a0; sidx[t][1] = a1; sidx[t][2] = a2;
        sw[t][0] = w0; sw[t][1] = w1; sw[t][2] = w2;
    }

    // Xt cols [0,128) from btile (overlaps the t<32 merge)
    unsigned short* Xb = Xt + ((size_t)b * 4096 + n0) * 384;
    {
        int nn = t >> 3, cs = (t & 7) * 16;
        short8 v0 = *(const short8*)&btile[nn][cs];
        short8 v1 = *(const short8*)&btile[nn][cs + 8];
        unsigned short* dst = Xb + (size_t)nn * 384 + cs;
        *(short8*)dst = v0;
        *(short8*)(dst + 8) = v1;
    }
    __syncthreads();   // sidx/sw visible

    // interpolation -> Xt cols [128,384); 8 lanes x 32 ch per point
    {
        int nn = t >> 3, cs = (t & 7) * 32;
        const unsigned short* pb = p2t + (size_t)b * 1024 * 256 + cs;
        const unsigned short* r0 = pb + (size_t)sidx[nn][0] * 256;
        const unsigned short* r1 = pb + (size_t)sidx[nn][1] * 256;
        const unsigned short* r2 = pb + (size_t)sidx[nn][2] * 256;
        float w0 = sw[nn][0], w1 = sw[nn][1], w2 = sw[nn][2];
        unsigned short* dst = Xb + (size_t)nn * 384 + 128 + cs;
        #pragma unroll
        for (int j = 0; j < 4; ++j) {
            short8 a = *(const short8*)(r0 + j * 8);
            short8 bb = *(const short8*)(r1 + j * 8);
            short8 cc = *(const short8*)(r2 + j * 8);
            short8 o;
            #pragma unroll
            for (int e = 0; e < 8; ++e) {
                float v = w0 * bf2f((unsigned short)a[e]) + w1 * bf2f((unsigned short)bb[e])
                        + w2 * bf2f((unsigned short)cc[e]);
                o[e] = (short)f2bf(v);
            }
            *(short8*)(dst + j * 8) = o;
        }
    }
}

// ---------- wide GEMM 128x256 with fused BN-stats epilogue ----------
// C[ar][bc] = sum_k A[ar][k]*B[bc][k], A,B row-major [rows][Kdim] bf16.
// out index = arow*sA + (brow>>12)*sBatch + (brow&4095)
// SMODE 1 (GEMM1): grid (Ablocks, 1);   ar0 = bx*128, br0 = 0.
//   partials per B-col over block's 128 A-rows: psp[bx*256 + col]
// SMODE 2 (GEMM2): grid (Bblocks, 2);   ar0 = by*128, br0 = bx*256.
//   partials per A-row over block's 256 B-rows: psp[bx*256 + ar0 + row]
template<int SMODE>
__global__ __launch_bounds__(256, 2) void k_gemm(const unsigned short* __restrict__ A,
        const unsigned short* __restrict__ B, unsigned short* __restrict__ C,
        int Kdim, size_t sA, size_t sBatch,
        float* __restrict__ psp, float* __restrict__ pqp) {
    __shared__ unsigned short lA[128 * 32];
    __shared__ unsigned short lB[256 * 32];
    __shared__ float sredS[4][128];
    __shared__ float sredQ[4][128];
    int t = threadIdx.x;
    int w = t >> 6, lane = t & 63;
    int ar0 = (SMODE == 1 ? blockIdx.x : blockIdx.y) * 128;
    int br0 = (SMODE == 1 ? blockIdx.y : blockIdx.x) * 256;
    int war = (w >> 1) * 64, wbr = (w & 1) * 128;
    f32x4 acc[4][8] = {};
    int rlo = lane & 15, khi = lane >> 4;
    for (int kk = 0; kk < Kdim; kk += 32) {
        #pragma unroll
        for (int it = 0; it < 2; ++it) {
            int qq = it * 256 + w * 64 + lane;
            int row = qq >> 2, kc = qq & 3;
            const unsigned short* srcA = A + (size_t)(ar0 + row) * Kdim + kk + ((kc ^ (row & 3)) << 3);
            gload_lds16(srcA, &lA[(size_t)(it * 256 + w * 64) * 8]);
        }
        #pragma unroll
        for (int it = 0; it < 4; ++it) {
            int qq = it * 256 + w * 64 + lane;
            int row = qq >> 2, kc = qq & 3;
            const unsigned short* srcB = B + (size_t)(br0 + row) * Kdim + kk + ((kc ^ (row & 3)) << 3);
            gload_lds16(srcB, &lB[(size_t)(it * 256 + w * 64) * 8]);
        }
        __syncthreads();
        short8 af[4], bfr[8];
        #pragma unroll
        for (int mi = 0; mi < 4; ++mi) {
            int r = war + mi * 16 + rlo;
            af[mi] = *(const short8*)&lA[(size_t)(r * 4 + (khi ^ (r & 3))) * 8];
        }
        #pragma unroll
        for (int ni = 0; ni < 8; ++ni) {
            int r = wbr + ni * 16 + rlo;
            bfr[ni] = *(const short8*)&lB[(size_t)(r * 4 + (khi ^ (r & 3))) * 8];
        }
        #pragma unroll
        for (int mi = 0; mi < 4; ++mi)
            #pragma unroll
            for (int ni = 0; ni < 8; ++ni)
                acc[mi][ni] = __builtin_amdgcn_mfma_f32_16x16x32_bf16(af[mi], bfr[ni], acc[mi][ni], 0, 0, 0);
        __syncthreads();
    }
    // C write
    #pragma unroll
    for (int mi = 0; mi < 4; ++mi) {
        #pragma unroll
        for (int ni = 0; ni < 8; ++ni) {
            #pragma unroll
            for (int r = 0; r < 4; ++r) {
                int arow = ar0 + war + mi * 16 + khi * 4 + r;
                int brow = br0 + wbr + ni * 16 + rlo;
                size_t oidx = (size_t)arow * sA + (size_t)(brow >> 12) * sBatch + (size_t)(brow & 4095);
                C[oidx] = f2bf(acc[mi][ni][r]);
            }
        }
    }
    // fused BN stats (f32 accumulators, deterministic per-block partials)
    if constexpr (SMODE == 1) {
        // per B-col sums over this block's 128 A-rows
        #pragma unroll
        for (int ni = 0; ni < 8; ++ni) {
            float s = 0.f, qs = 0.f;
            #pragma unroll
            for (int mi = 0; mi < 4; ++mi)
                #pragma unroll
                for (int r = 0; r < 4; ++r) { float v = acc[mi][ni][r]; s += v; qs += v * v; }
            s += __shfl_xor(s, 16); qs += __shfl_xor(qs, 16);
            s += __shfl_xor(s, 32); qs += __shfl_xor(qs, 32);
            if (khi == 0) { sredS[w][ni * 16 + rlo] = s; sredQ[w][ni * 16 + rlo] = qs; }
        }
        __syncthreads();
        {
            int c = t;  // 0..255
            float s, qs;
            if (c < 128) { s = sredS[0][c] + sredS[2][c]; qs = sredQ[0][c] + sredQ[2][c]; }
            else { s = sredS[1][c - 128] + sredS[3][c - 128]; qs = sredQ[1][c - 128] + sredQ[3][c - 128]; }
            size_t pi = (size_t)blockIdx.x * 256 + c;
            psp[pi] = s; pqp[pi] = qs;
        }
    } else {
        // per A-row sums over this block's 256 B-rows
        float rs[4][4], rq[4][4];
        #pragma unroll
        for (int mi = 0; mi < 4; ++mi) {
            #pragma unroll
            for (int r = 0; r < 4; ++r) {
                float s = 0.f, qs = 0.f;
                #pragma unroll
                for (int ni = 0; ni < 8; ++ni) { float v = acc[mi][ni][r]; s += v; qs += v * v; }
                s += __shfl_xor(s, 1); qs += __shfl_xor(qs, 1);
                s += __shfl_xor(s, 2); qs += __shfl_xor(qs, 2);
                s += __shfl_xor(s, 4); qs += __shfl_xor(qs, 4);
                s += __shfl_xor(s, 8); qs += __shfl_xor(qs, 8);
                rs[mi][r] = s; rq[mi][r] = qs;
            }
        }
        if (rlo == 0) {
            #pragma unroll
            for (int mi = 0; mi < 4; ++mi)
                #pragma unroll
                for (int r = 0; r < 4; ++r) {
                    sredS[w][mi * 16 + khi * 4 + r] = rs[mi][r];
                    sredQ[w][mi * 16 + khi * 4 + r] = rq[mi][r];
                }
        }
        __syncthreads();
        if (t < 128) {
            float s, qs;
            if (t < 64) { s = sredS[0][t] + sredS[1][t]; qs = sredQ[0][t] + sredQ[1][t]; }
            else { s = sredS[2][t - 64] + sredS[3][t - 64]; qs = sredQ[2][t - 64] + sredQ[3][t - 64]; }
            size_t pi = (size_t)blockIdx.x * 256 + ar0 + t;
            psp[pi] = s; pqp[pi] = qs;
        }
    }
}

// ---------- finalize BN coefficients from npart partials ----------
__global__ __launch_bounds__(256) void k_fin(const float* __restrict__ ps,
        const float* __restrict__ pq, const float* __restrict__ g,
        const float* __restrict__ be, float* __restrict__ av, float* __restrict__ bv,
        int npart) {
    int c = threadIdx.x;
    float s = 0.f, q = 0.f;
    for (int i = 0; i < npart; ++i) { s += ps[i * 256 + c]; q += pq[i * 256 + c]; }
    float mean = s / 65536.0f;
    float var = q / 65536.0f - mean * mean;
    float a = g[c] * rsqrtf(var + BN_EPS);
    av[c] = a; bv[c] = be[c] - mean * a;
}

// ---------- normalize+relu h1 in place ----------
__global__ __launch_bounds__(256) void k_norm1(unsigned short* __restrict__ h1,
        const float* __restrict__ av, const float* __restrict__ bv) {
    size_t i0 = ((size_t)blockIdx.x * 256 + threadIdx.x) * 8;
    int c0 = (int)(i0 & 255);
    short8 v = *(short8*)&h1[i0];
    short8 o;
    #pragma unroll
    for (int j = 0; j < 8; ++j) {
        float x = bf2f((unsigned short)v[j]);
        float y = av[c0 + j] * x + bv[c0 + j];
        o[j] = (short)f2bf(fmaxf(y, 0.f));
    }
    *(short8*)&h1[i0] = o;
}

// ---------- final normalize+relu -> f32 out ----------
__global__ __launch_bounds__(256) void k_final(const unsigned short* __restrict__ h2,
        const float* __restrict__ av, const float* __restrict__ bv, float* __restrict__ out) {
    size_t i0 = ((size_t)blockIdx.x * 256 + threadIdx.x) * 8;
    int o = (int)((i0 >> 12) & 255);
    float a = av[o], b = bv[o];
    short8 v = *(const short8*)&h2[i0];
    f32x4 r0, r1;
    #pragma unroll
    for (int j = 0; j < 4; ++j) r0[j] = fmaxf(a * bf2f((unsigned short)v[j]) + b, 0.f);
    #pragma unroll
    for (int j = 0; j < 4; ++j) r1[j] = fmaxf(a * bf2f((unsigned short)v[4 + j]) + b, 0.f);
    *(f32x4*)&out[i0] = r0;
    *(f32x4*)&out[i0 + 4] = r1;
}

extern "C" void kernel_launch(void* const* d_in, const int* in_sizes, int n_in,
                              void* d_out, int out_size, void* d_ws, size_t ws_size,
                              hipStream_t stream) {
    const float* xyz1 = (const float*)d_in[0];
    const float* xyz2 = (const float*)d_in[1];
    const float* p1   = (const float*)d_in[2];
    const float* p2   = (const float*)d_in[3];
    const float* W1   = (const float*)d_in[4];
    const float* g1   = (const float*)d_in[5];
    const float* be1  = (const float*)d_in[6];
    const float* W2   = (const float*)d_in[7];
    const float* g2   = (const float*)d_in[8];
    const float* be2  = (const float*)d_in[9];
    float* out = (float*)d_out;
    char* ws = (char*)d_ws;

    unsigned short* Xt  = (unsigned short*)(ws);                    // 50,331,648 B
    unsigned short* h1  = (unsigned short*)(ws + 50331648);         // 33,554,432 B
    unsigned short* h2  = (unsigned short*)(ws + 83886080);         // 33,554,432 B
    // p2t shares h2's slot: dead before GEMM2 writes h2
    unsigned short* p2t = (unsigned short*)(ws + 83886080);         // 8,388,608 B
    unsigned short* W1b = (unsigned short*)(ws + 117440512);        // 196,608 B
    unsigned short* W2b = (unsigned short*)(ws + 117637120);        // 131,072 B
    float* ps1p = (float*)(ws + 117768192);                         // 524,288 B
    float* pq1p = (float*)(ws + 118292480);                         // 524,288 B
    float* ps2p = (float*)(ws + 118816768);                         // 524,288 B
    float* pq2p = (float*)(ws + 119341056);                         // 524,288 B
    float* a1v  = (float*)(ws + 119865344);
    float* b1v  = (float*)(ws + 119866368);
    float* a2v  = (float*)(ws + 119867392);
    float* b2v  = (float*)(ws + 119868416);

    k_convert<<<dim3(384), dim3(256), 0, stream>>>(W1, W2, W1b, W2b);
    k_tr_p2<<<dim3(64, 16), dim3(256), 0, stream>>>(p2, p2t);
    k_knnbuild<<<dim3(128, 16), dim3(256), 0, stream>>>(xyz1, xyz2, p1, p2t, Xt);
    // GEMM1: A = Xt (65536 x 384), B = W1b (256 x 384, full 256-tile) -> h1[n][o], + stats per o
    k_gemm<1><<<dim3(512, 1), dim3(256), 0, stream>>>(Xt, W1b, h1, 384, 256, 0, ps1p, pq1p);
    k_fin<<<dim3(1), dim3(256), 0, stream>>>(ps1p, pq1p, g1, be1, a1v, b1v, 512);
    k_norm1<<<dim3(8192), dim3(256), 0, stream>>>(h1, a1v, b1v);
    // GEMM2: A = W2b (256 x 256), B = h1n (65536 x 256) -> h2[b][o][n], + stats per o
    // grid: B-tile fastest (x), A-half in y -> blocks sharing a B-slice land on same XCD
    k_gemm<2><<<dim3(256, 2), dim3(256), 0, stream>>>(W2b, h1, h2, 256, 4096, 1048576, ps2p, pq2p);
    k_fin<<<dim3(1), dim3(256), 0, stream>>>(ps2p, pq2p, g2, be2, a2v, b2v, 256);
    k_final<<<dim3(8192), dim3(256), 0, stream>>>(h2, a2v, b2v, out);
}

// Round 9
// 142.728 us; speedup vs baseline: 2.2959x; 2.2959x over previous
//
#include <hip/hip_runtime.h>
#include <hip/hip_bf16.h>

typedef __attribute__((ext_vector_type(8))) short short8;
typedef __attribute__((ext_vector_type(4))) float f32x4;

#define BN_EPS 1e-5f

// ---------- bf16 helpers (RNE) ----------
__device__ __forceinline__ float bf2f(unsigned short u) {
    unsigned int x = ((unsigned int)u) << 16;
    union { unsigned int i; float f; } c; c.i = x; return c.f;
}
__device__ __forceinline__ unsigned short f2bf(float f) {
    union { float f; unsigned int i; } c; c.f = f;
    unsigned int lsb = (c.i >> 16) & 1u;
    c.i += 0x7fffu + lsb;
    return (unsigned short)(c.i >> 16);
}
__device__ __forceinline__ unsigned long long pack4bf(float a, float b, float c, float d) {
    unsigned long long r = (unsigned long long)f2bf(a)
        | ((unsigned long long)f2bf(b) << 16)
        | ((unsigned long long)f2bf(c) << 32)
        | ((unsigned long long)f2bf(d) << 48);
    return r;
}

// ---------- async global->LDS 16B ----------
typedef const unsigned int __attribute__((address_space(1)))* gas_t;
typedef unsigned int __attribute__((address_space(3)))* las_t;
__device__ __forceinline__ void gload_lds16(const void* src, void* ldsdst) {
    __builtin_amdgcn_global_load_lds((gas_t)src, (las_t)ldsdst, 16, 0, 0);
}

// ---------- convert weights to bf16 ----------
__global__ __launch_bounds__(256) void k_convert(const float* __restrict__ W1,
        const float* __restrict__ W2, unsigned short* __restrict__ W1b,
        unsigned short* __restrict__ W2b) {
    int i = blockIdx.x * 256 + threadIdx.x;
    if (i < 256 * 384) W1b[i] = f2bf(W1[i]);
    if (i < 256 * 256) W2b[i] = f2bf(W2[i]);
}

// ---------- transpose p2 [b][256][1024] f32 -> p2t [b][1024][256] bf16 ----------
__global__ __launch_bounds__(256) void k_tr_p2(const float* __restrict__ p2,
        unsigned short* __restrict__ p2t) {
    __shared__ unsigned short btile[32][136];
    int b = blockIdx.y;
    int n0 = (blockIdx.x & 31) * 32;
    int c0 = (blockIdx.x >> 5) * 128;
    int t = threadIdx.x;
    const float* src = p2 + (size_t)b * 256 * 1024 + (size_t)c0 * 1024 + n0;
    int c4 = (t >> 3) * 4, n4 = (t & 7) * 4;
    f32x4 q0 = *(const f32x4*)&src[(size_t)(c4 + 0) * 1024 + n4];
    f32x4 q1 = *(const f32x4*)&src[(size_t)(c4 + 1) * 1024 + n4];
    f32x4 q2 = *(const f32x4*)&src[(size_t)(c4 + 2) * 1024 + n4];
    f32x4 q3 = *(const f32x4*)&src[(size_t)(c4 + 3) * 1024 + n4];
    #pragma unroll
    for (int j = 0; j < 4; ++j) {
        *(unsigned long long*)&btile[n4 + j][c4] = pack4bf(q0[j], q1[j], q2[j], q3[j]);
    }
    __syncthreads();
    int nn = t >> 3, cs = (t & 7) * 16;
    short8 v0 = *(const short8*)&btile[nn][cs];
    short8 v1 = *(const short8*)&btile[nn][cs + 8];
    unsigned short* dst = p2t + ((size_t)b * 1024 + n0 + nn) * 256 + c0 + cs;
    *(short8*)dst = v0;
    *(short8*)(dst + 8) = v1;
}

// ---------- fused 3-NN + build: Xt[b*4096+n][384] = concat(points1^T, interp) ----------
__global__ __launch_bounds__(256) void k_knnbuild(const float* __restrict__ xyz1,
        const float* __restrict__ xyz2, const float* __restrict__ p1,
        const unsigned short* __restrict__ p2t, unsigned short* __restrict__ Xt) {
    __shared__ f32x4 cand[1024];          // (x, y, z, |p|^2)
    __shared__ float mkd[32][25];         // 24 partial dists per query (+pad)
    __shared__ int   mki[32][25];         // 24 partial indices per query (+pad)
    __shared__ unsigned short btile[32][136];
    __shared__ int sidx[32][3];
    __shared__ float sw[32][3];
    int b = blockIdx.y;
    int n0 = blockIdx.x * 32;
    int t = threadIdx.x;

    // issue p1 loads early: they complete under the VALU-bound scan
    const float* p1b = p1 + (size_t)b * 128 * 4096 + n0;
    int c4 = (t >> 3) * 4, n4 = (t & 7) * 4;
    f32x4 q0 = *(const f32x4*)&p1b[(size_t)(c4 + 0) * 4096 + n4];
    f32x4 q1 = *(const f32x4*)&p1b[(size_t)(c4 + 1) * 4096 + n4];
    f32x4 q2 = *(const f32x4*)&p1b[(size_t)(c4 + 2) * 4096 + n4];
    f32x4 q3 = *(const f32x4*)&p1b[(size_t)(c4 + 3) * 4096 + n4];

    const float* x2 = xyz2 + (size_t)b * 3072;
    for (int i = t; i < 1024; i += 256) {
        float x = x2[i], y = x2[1024 + i], z = x2[2048 + i];
        f32x4 v;
        v[0] = x; v[1] = y; v[2] = z; v[3] = x * x + y * y + z * z;
        cand[i] = v;
    }
    __syncthreads();

    // scan: 8 splits x 128 candidates, exact-f32 branchless top-3
    int q = t & 31, s = t >> 5;
    int n = n0 + q;
    const float* x1 = xyz1 + (size_t)b * 12288;
    float px = x1[n], py = x1[4096 + n], pz = x1[8192 + n];
    float s1 = px * px + py * py + pz * pz;
    float d0 = 1e30f, d1 = 1e30f, d2 = 1e30f;
    int i0 = 0, i1 = 0, i2 = 0;
    int j0 = s * 128;
    #pragma unroll 4
    for (int jj = 0; jj < 128; ++jj) {
        int j = j0 + jj;
        f32x4 v = cand[j];
        // exact same expression tree as the passing serial version:
        float dot = px * v[0] + py * v[1] + pz * v[2];
        float d = -2.0f * dot; d += s1; d += v[3];
        bool b0 = d < d0, b1 = d < d1, b2 = d < d2;
        d2 = b1 ? d1 : (b2 ? d : d2);
        i2 = b1 ? i1 : (b2 ? j : i2);
        d1 = b0 ? d0 : (b1 ? d : d1);
        i1 = b0 ? i0 : (b1 ? j : i1);
        d0 = b0 ? d : d0;
        i0 = b0 ? j : i0;
    }
    mkd[q][s * 3 + 0] = d0; mki[q][s * 3 + 0] = i0;
    mkd[q][s * 3 + 1] = d1; mki[q][s * 3 + 1] = i1;
    mkd[q][s * 3 + 2] = d2; mki[q][s * 3 + 2] = i2;

    // p1 transpose into LDS (loads issued at top are done by now)
    #pragma unroll
    for (int j = 0; j < 4; ++j) {
        *(unsigned long long*)&btile[n4 + j][c4] = pack4bf(q0[j], q1[j], q2[j], q3[j]);
    }
    __syncthreads();   // covers mkd/mki partials AND btile

    // merge 24 partials (t<32) in ascending split (=index) order;
    // strict < keeps the earlier (lower-index) entry on ties, matching top_k.
    if (t < 32) {
        float e0 = 1e30f, e1 = 1e30f, e2 = 1e30f;
        int a0 = 0, a1 = 0, a2 = 0;
        #pragma unroll
        for (int m = 0; m < 24; ++m) {
            float d = mkd[t][m]; int j = mki[t][m];
            bool b0 = d < e0, b1 = d < e1, b2 = d < e2;
            e2 = b1 ? e1 : (b2 ? d : e2);
            a2 = b1 ? a1 : (b2 ? j : a2);
            e1 = b0 ? e0 : (b1 ? d : e1);
            a1 = b0 ? a0 : (b1 ? j : a1);
            e0 = b0 ? d : e0;
            a0 = b0 ? j : a0;
        }
        float dd0 = fmaxf(e0, 1e-10f), dd1 = fmaxf(e1, 1e-10f), dd2 = fmaxf(e2, 1e-10f);
        float w0 = 1.f / dd0, w1 = 1.f / dd1, w2 = 1.f / dd2;
        float swt = w0 + w1 + w2; w0 /= swt; w1 /= swt; w2 /= swt;
        sidx[t][0] = a0; sidx[t][1] = a1; sidx[t][2] = a2;
        sw[t][0] = w0; sw[t][1] = w1; sw[t][2] = w2;
    }

    // Xt cols [0,128) from btile (overlaps the t<32 merge)
    unsigned short* Xb = Xt + ((size_t)b * 4096 + n0) * 384;
    {
        int nn = t >> 3, cs = (t & 7) * 16;
        short8 v0 = *(const short8*)&btile[nn][cs];
        short8 v1 = *(const short8*)&btile[nn][cs + 8];
        unsigned short* dst = Xb + (size_t)nn * 384 + cs;
        *(short8*)dst = v0;
        *(short8*)(dst + 8) = v1;
    }
    __syncthreads();   // sidx/sw visible

    // interpolation -> Xt cols [128,384); 8 lanes x 32 ch per point
    {
        int nn = t >> 3, cs = (t & 7) * 32;
        const unsigned short* pb = p2t + (size_t)b * 1024 * 256 + cs;
        const unsigned short* r0 = pb + (size_t)sidx[nn][0] * 256;
        const unsigned short* r1 = pb + (size_t)sidx[nn][1] * 256;
        const unsigned short* r2 = pb + (size_t)sidx[nn][2] * 256;
        float w0 = sw[nn][0], w1 = sw[nn][1], w2 = sw[nn][2];
        unsigned short* dst = Xb + (size_t)nn * 384 + 128 + cs;
        #pragma unroll
        for (int j = 0; j < 4; ++j) {
            short8 a = *(const short8*)(r0 + j * 8);
            short8 bb = *(const short8*)(r1 + j * 8);
            short8 cc = *(const short8*)(r2 + j * 8);
            short8 o;
            #pragma unroll
            for (int e = 0; e < 8; ++e) {
                float v = w0 * bf2f((unsigned short)a[e]) + w1 * bf2f((unsigned short)bb[e])
                        + w2 * bf2f((unsigned short)cc[e]);
                o[e] = (short)f2bf(v);
            }
            *(short8*)(dst + j * 8) = o;
        }
    }
}

// ---------- wide GEMM 128x256 with fused BN-stats epilogue ----------
// C[ar][bc] = sum_k A[ar][k]*B[bc][k], A,B row-major [rows][Kdim] bf16.
// out index = arow*sA + (brow>>12)*sBatch + (brow&4095)
// SMODE 1 (GEMM1): grid (Ablocks, 1);   ar0 = bx*128, br0 = 0.
//   partials per B-col over block's 128 A-rows: psp[bx*256 + col]
// SMODE 2 (GEMM2): grid (Bblocks, 2);   ar0 = by*128, br0 = bx*256.
//   partials per A-row over block's 256 B-rows: psp[bx*256 + ar0 + row]
template<int SMODE>
__global__ __launch_bounds__(256, 2) void k_gemm(const unsigned short* __restrict__ A,
        const unsigned short* __restrict__ B, unsigned short* __restrict__ C,
        int Kdim, size_t sA, size_t sBatch,
        float* __restrict__ psp, float* __restrict__ pqp) {
    __shared__ unsigned short lA[128 * 32];
    __shared__ unsigned short lB[256 * 32];
    __shared__ float sredS[4][128];
    __shared__ float sredQ[4][128];
    int t = threadIdx.x;
    int w = t >> 6, lane = t & 63;
    int ar0 = (SMODE == 1 ? blockIdx.x : blockIdx.y) * 128;
    int br0 = (SMODE == 1 ? blockIdx.y : blockIdx.x) * 256;
    int war = (w >> 1) * 64, wbr = (w & 1) * 128;
    f32x4 acc[4][8] = {};
    int rlo = lane & 15, khi = lane >> 4;
    for (int kk = 0; kk < Kdim; kk += 32) {
        #pragma unroll
        for (int it = 0; it < 2; ++it) {
            int qq = it * 256 + w * 64 + lane;
            int row = qq >> 2, kc = qq & 3;
            const unsigned short* srcA = A + (size_t)(ar0 + row) * Kdim + kk + ((kc ^ (row & 3)) << 3);
            gload_lds16(srcA, &lA[(size_t)(it * 256 + w * 64) * 8]);
        }
        #pragma unroll
        for (int it = 0; it < 4; ++it) {
            int qq = it * 256 + w * 64 + lane;
            int row = qq >> 2, kc = qq & 3;
            const unsigned short* srcB = B + (size_t)(br0 + row) * Kdim + kk + ((kc ^ (row & 3)) << 3);
            gload_lds16(srcB, &lB[(size_t)(it * 256 + w * 64) * 8]);
        }
        __syncthreads();
        short8 af[4], bfr[8];
        #pragma unroll
        for (int mi = 0; mi < 4; ++mi) {
            int r = war + mi * 16 + rlo;
            af[mi] = *(const short8*)&lA[(size_t)(r * 4 + (khi ^ (r & 3))) * 8];
        }
        #pragma unroll
        for (int ni = 0; ni < 8; ++ni) {
            int r = wbr + ni * 16 + rlo;
            bfr[ni] = *(const short8*)&lB[(size_t)(r * 4 + (khi ^ (r & 3))) * 8];
        }
        #pragma unroll
        for (int mi = 0; mi < 4; ++mi)
            #pragma unroll
            for (int ni = 0; ni < 8; ++ni)
                acc[mi][ni] = __builtin_amdgcn_mfma_f32_16x16x32_bf16(af[mi], bfr[ni], acc[mi][ni], 0, 0, 0);
        __syncthreads();
    }
    // C write
    #pragma unroll
    for (int mi = 0; mi < 4; ++mi) {
        #pragma unroll
        for (int ni = 0; ni < 8; ++ni) {
            #pragma unroll
            for (int r = 0; r < 4; ++r) {
                int arow = ar0 + war + mi * 16 + khi * 4 + r;
                int brow = br0 + wbr + ni * 16 + rlo;
                size_t oidx = (size_t)arow * sA + (size_t)(brow >> 12) * sBatch + (size_t)(brow & 4095);
                C[oidx] = f2bf(acc[mi][ni][r]);
            }
        }
    }
    // fused BN stats (f32 accumulators, deterministic per-block partials)
    if constexpr (SMODE == 1) {
        // per B-col sums over this block's 128 A-rows
        #pragma unroll
        for (int ni = 0; ni < 8; ++ni) {
            float s = 0.f, qs = 0.f;
            #pragma unroll
            for (int mi = 0; mi < 4; ++mi)
                #pragma unroll
                for (int r = 0; r < 4; ++r) { float v = acc[mi][ni][r]; s += v; qs += v * v; }
            s += __shfl_xor(s, 16); qs += __shfl_xor(qs, 16);
            s += __shfl_xor(s, 32); qs += __shfl_xor(qs, 32);
            if (khi == 0) { sredS[w][ni * 16 + rlo] = s; sredQ[w][ni * 16 + rlo] = qs; }
        }
        __syncthreads();
        {
            int c = t;  // 0..255
            float s, qs;
            if (c < 128) { s = sredS[0][c] + sredS[2][c]; qs = sredQ[0][c] + sredQ[2][c]; }
            else { s = sredS[1][c - 128] + sredS[3][c - 128]; qs = sredQ[1][c - 128] + sredQ[3][c - 128]; }
            size_t pi = (size_t)blockIdx.x * 256 + c;
            psp[pi] = s; pqp[pi] = qs;
        }
    } else {
        // per A-row sums over this block's 256 B-rows
        float rs[4][4], rq[4][4];
        #pragma unroll
        for (int mi = 0; mi < 4; ++mi) {
            #pragma unroll
            for (int r = 0; r < 4; ++r) {
                float s = 0.f, qs = 0.f;
                #pragma unroll
                for (int ni = 0; ni < 8; ++ni) { float v = acc[mi][ni][r]; s += v; qs += v * v; }
                s += __shfl_xor(s, 1); qs += __shfl_xor(qs, 1);
                s += __shfl_xor(s, 2); qs += __shfl_xor(qs, 2);
                s += __shfl_xor(s, 4); qs += __shfl_xor(qs, 4);
                s += __shfl_xor(s, 8); qs += __shfl_xor(qs, 8);
                rs[mi][r] = s; rq[mi][r] = qs;
            }
        }
        if (rlo == 0) {
            #pragma unroll
            for (int mi = 0; mi < 4; ++mi)
                #pragma unroll
                for (int r = 0; r < 4; ++r) {
                    sredS[w][mi * 16 + khi * 4 + r] = rs[mi][r];
                    sredQ[w][mi * 16 + khi * 4 + r] = rq[mi][r];
                }
        }
        __syncthreads();
        if (t < 128) {
            float s, qs;
            if (t < 64) { s = sredS[0][t] + sredS[1][t]; qs = sredQ[0][t] + sredQ[1][t]; }
            else { s = sredS[2][t - 64] + sredS[3][t - 64]; qs = sredQ[2][t - 64] + sredQ[3][t - 64]; }
            size_t pi = (size_t)blockIdx.x * 256 + ar0 + t;
            psp[pi] = s; pqp[pi] = qs;
        }
    }
}

// ---------- finalize BN coefficients: one block per channel, parallel over partials ----------
__global__ __launch_bounds__(256) void k_fin(const float* __restrict__ ps,
        const float* __restrict__ pq, const float* __restrict__ g,
        const float* __restrict__ be, float* __restrict__ av, float* __restrict__ bv,
        int npart) {
    int c = blockIdx.x;
    int t = threadIdx.x;
    float s = 0.f, q = 0.f;
    for (int i = t; i < npart; i += 256) {
        s += ps[(size_t)i * 256 + c];
        q += pq[(size_t)i * 256 + c];
    }
    #pragma unroll
    for (int off = 32; off; off >>= 1) { s += __shfl_down(s, off); q += __shfl_down(q, off); }
    __shared__ float ss[4], sq[4];
    if ((t & 63) == 0) { ss[t >> 6] = s; sq[t >> 6] = q; }
    __syncthreads();
    if (t == 0) {
        float S = ss[0] + ss[1] + ss[2] + ss[3];
        float Q = sq[0] + sq[1] + sq[2] + sq[3];
        float mean = S / 65536.0f;
        float var = Q / 65536.0f - mean * mean;
        float a = g[c] * rsqrtf(var + BN_EPS);
        av[c] = a; bv[c] = be[c] - mean * a;
    }
}

// ---------- normalize+relu h1 in place ----------
__global__ __launch_bounds__(256) void k_norm1(unsigned short* __restrict__ h1,
        const float* __restrict__ av, const float* __restrict__ bv) {
    size_t i0 = ((size_t)blockIdx.x * 256 + threadIdx.x) * 8;
    int c0 = (int)(i0 & 255);
    short8 v = *(short8*)&h1[i0];
    short8 o;
    #pragma unroll
    for (int j = 0; j < 8; ++j) {
        float x = bf2f((unsigned short)v[j]);
        float y = av[c0 + j] * x + bv[c0 + j];
        o[j] = (short)f2bf(fmaxf(y, 0.f));
    }
    *(short8*)&h1[i0] = o;
}

// ---------- final normalize+relu -> f32 out ----------
__global__ __launch_bounds__(256) void k_final(const unsigned short* __restrict__ h2,
        const float* __restrict__ av, const float* __restrict__ bv, float* __restrict__ out) {
    size_t i0 = ((size_t)blockIdx.x * 256 + threadIdx.x) * 8;
    int o = (int)((i0 >> 12) & 255);
    float a = av[o], b = bv[o];
    short8 v = *(const short8*)&h2[i0];
    f32x4 r0, r1;
    #pragma unroll
    for (int j = 0; j < 4; ++j) r0[j] = fmaxf(a * bf2f((unsigned short)v[j]) + b, 0.f);
    #pragma unroll
    for (int j = 0; j < 4; ++j) r1[j] = fmaxf(a * bf2f((unsigned short)v[4 + j]) + b, 0.f);
    *(f32x4*)&out[i0] = r0;
    *(f32x4*)&out[i0 + 4] = r1;
}

extern "C" void kernel_launch(void* const* d_in, const int* in_sizes, int n_in,
                              void* d_out, int out_size, void* d_ws, size_t ws_size,
                              hipStream_t stream) {
    const float* xyz1 = (const float*)d_in[0];
    const float* xyz2 = (const float*)d_in[1];
    const float* p1   = (const float*)d_in[2];
    const float* p2   = (const float*)d_in[3];
    const float* W1   = (const float*)d_in[4];
    const float* g1   = (const float*)d_in[5];
    const float* be1  = (const float*)d_in[6];
    const float* W2   = (const float*)d_in[7];
    const float* g2   = (const float*)d_in[8];
    const float* be2  = (const float*)d_in[9];
    float* out = (float*)d_out;
    char* ws = (char*)d_ws;

    unsigned short* Xt  = (unsigned short*)(ws);                    // 50,331,648 B
    unsigned short* h1  = (unsigned short*)(ws + 50331648);         // 33,554,432 B
    unsigned short* h2  = (unsigned short*)(ws + 83886080);         // 33,554,432 B
    // p2t shares h2's slot: dead before GEMM2 writes h2
    unsigned short* p2t = (unsigned short*)(ws + 83886080);         // 8,388,608 B
    unsigned short* W1b = (unsigned short*)(ws + 117440512);        // 196,608 B
    unsigned short* W2b = (unsigned short*)(ws + 117637120);        // 131,072 B
    float* ps1p = (float*)(ws + 117768192);                         // 524,288 B
    float* pq1p = (float*)(ws + 118292480);                         // 524,288 B
    float* ps2p = (float*)(ws + 118816768);                         // 524,288 B
    float* pq2p = (float*)(ws + 119341056);                         // 524,288 B
    float* a1v  = (float*)(ws + 119865344);
    float* b1v  = (float*)(ws + 119866368);
    float* a2v  = (float*)(ws + 119867392);
    float* b2v  = (float*)(ws + 119868416);

    k_convert<<<dim3(384), dim3(256), 0, stream>>>(W1, W2, W1b, W2b);
    k_tr_p2<<<dim3(64, 16), dim3(256), 0, stream>>>(p2, p2t);
    k_knnbuild<<<dim3(128, 16), dim3(256), 0, stream>>>(xyz1, xyz2, p1, p2t, Xt);
    // GEMM1: A = Xt (65536 x 384), B = W1b (256 x 384, full 256-tile) -> h1[n][o], + stats per o
    k_gemm<1><<<dim3(512, 1), dim3(256), 0, stream>>>(Xt, W1b, h1, 384, 256, 0, ps1p, pq1p);
    k_fin<<<dim3(256), dim3(256), 0, stream>>>(ps1p, pq1p, g1, be1, a1v, b1v, 512);
    k_norm1<<<dim3(8192), dim3(256), 0, stream>>>(h1, a1v, b1v);
    // GEMM2: A = W2b (256 x 256), B = h1n (65536 x 256) -> h2[b][o][n], + stats per o
    k_gemm<2><<<dim3(256, 2), dim3(256), 0, stream>>>(W2b, h1, h2, 256, 4096, 1048576, ps2p, pq2p);
    k_fin<<<dim3(256), dim3(256), 0, stream>>>(ps2p, pq2p, g2, be2, a2v, b2v, 256);
    k_final<<<dim3(8192), dim3(256), 0, stream>>>(h2, a2v, b2v, out);
}

// Round 10
// 138.796 us; speedup vs baseline: 2.3610x; 1.0283x over previous
//
#include <hip/hip_runtime.h>
#include <hip/hip_bf16.h>

typedef __attribute__((ext_vector_type(8))) short short8;
typedef __attribute__((ext_vector_type(4))) float f32x4;

#define BN_EPS 1e-5f

// ---------- bf16 helpers (RNE) ----------
__device__ __forceinline__ float bf2f(unsigned short u) {
    unsigned int x = ((unsigned int)u) << 16;
    union { unsigned int i; float f; } c; c.i = x; return c.f;
}
__device__ __forceinline__ unsigned short f2bf(float f) {
    union { float f; unsigned int i; } c; c.f = f;
    unsigned int lsb = (c.i >> 16) & 1u;
    c.i += 0x7fffu + lsb;
    return (unsigned short)(c.i >> 16);
}
__device__ __forceinline__ unsigned long long pack4bf(float a, float b, float c, float d) {
    unsigned long long r = (unsigned long long)f2bf(a)
        | ((unsigned long long)f2bf(b) << 16)
        | ((unsigned long long)f2bf(c) << 32)
        | ((unsigned long long)f2bf(d) << 48);
    return r;
}

// ---------- async global->LDS 16B ----------
typedef const unsigned int __attribute__((address_space(1)))* gas_t;
typedef unsigned int __attribute__((address_space(3)))* las_t;
__device__ __forceinline__ void gload_lds16(const void* src, void* ldsdst) {
    __builtin_amdgcn_global_load_lds((gas_t)src, (las_t)ldsdst, 16, 0, 0);
}

// ---------- convert weights to bf16 ----------
__global__ __launch_bounds__(256) void k_convert(const float* __restrict__ W1,
        const float* __restrict__ W2, unsigned short* __restrict__ W1b,
        unsigned short* __restrict__ W2b) {
    int i = blockIdx.x * 256 + threadIdx.x;
    if (i < 256 * 384) W1b[i] = f2bf(W1[i]);
    if (i < 256 * 256) W2b[i] = f2bf(W2[i]);
}

// ---------- transpose p2 [b][256][1024] f32 -> p2t [b][1024][256] bf16 ----------
__global__ __launch_bounds__(256) void k_tr_p2(const float* __restrict__ p2,
        unsigned short* __restrict__ p2t) {
    __shared__ unsigned short btile[32][136];
    int b = blockIdx.y;
    int n0 = (blockIdx.x & 31) * 32;
    int c0 = (blockIdx.x >> 5) * 128;
    int t = threadIdx.x;
    const float* src = p2 + (size_t)b * 256 * 1024 + (size_t)c0 * 1024 + n0;
    int c4 = (t >> 3) * 4, n4 = (t & 7) * 4;
    f32x4 q0 = *(const f32x4*)&src[(size_t)(c4 + 0) * 1024 + n4];
    f32x4 q1 = *(const f32x4*)&src[(size_t)(c4 + 1) * 1024 + n4];
    f32x4 q2 = *(const f32x4*)&src[(size_t)(c4 + 2) * 1024 + n4];
    f32x4 q3 = *(const f32x4*)&src[(size_t)(c4 + 3) * 1024 + n4];
    #pragma unroll
    for (int j = 0; j < 4; ++j) {
        *(unsigned long long*)&btile[n4 + j][c4] = pack4bf(q0[j], q1[j], q2[j], q3[j]);
    }
    __syncthreads();
    int nn = t >> 3, cs = (t & 7) * 16;
    short8 v0 = *(const short8*)&btile[nn][cs];
    short8 v1 = *(const short8*)&btile[nn][cs + 8];
    unsigned short* dst = p2t + ((size_t)b * 1024 + n0 + nn) * 256 + c0 + cs;
    *(short8*)dst = v0;
    *(short8*)(dst + 8) = v1;
}

// ---------- fused 3-NN + build: Xt[b*4096+n][384] = concat(points1^T, interp) ----------
// LDS savings: btile (8.7KB) aliases cand (16KB) — cand is dead after the scan.
__global__ __launch_bounds__(256) void k_knnbuild(const float* __restrict__ xyz1,
        const float* __restrict__ xyz2, const float* __restrict__ p1,
        const unsigned short* __restrict__ p2t, unsigned short* __restrict__ Xt) {
    __shared__ f32x4 cand[1024];          // (x, y, z, |p|^2); later aliased as btile
    __shared__ float mkd[32][25];         // 24 partial dists per query (+pad)
    __shared__ int   mki[32][25];         // 24 partial indices per query (+pad)
    __shared__ int sidx[32][3];
    __shared__ float sw[32][3];
    unsigned short* btf = (unsigned short*)cand;   // btile alias: btf[r*136 + c]
    int b = blockIdx.y;
    int n0 = blockIdx.x * 32;
    int t = threadIdx.x;

    // issue p1 loads early: they complete under the VALU-bound scan
    const float* p1b = p1 + (size_t)b * 128 * 4096 + n0;
    int c4 = (t >> 3) * 4, n4 = (t & 7) * 4;
    f32x4 q0 = *(const f32x4*)&p1b[(size_t)(c4 + 0) * 4096 + n4];
    f32x4 q1 = *(const f32x4*)&p1b[(size_t)(c4 + 1) * 4096 + n4];
    f32x4 q2 = *(const f32x4*)&p1b[(size_t)(c4 + 2) * 4096 + n4];
    f32x4 q3 = *(const f32x4*)&p1b[(size_t)(c4 + 3) * 4096 + n4];

    const float* x2 = xyz2 + (size_t)b * 3072;
    for (int i = t; i < 1024; i += 256) {
        float x = x2[i], y = x2[1024 + i], z = x2[2048 + i];
        f32x4 v;
        v[0] = x; v[1] = y; v[2] = z; v[3] = x * x + y * y + z * z;
        cand[i] = v;
    }
    __syncthreads();   // (A) cand ready

    // scan: 8 splits x 128 candidates; exact-f32 branchless top-3.
    // med3/min float updates are bit-identical to the cndmask chain; index
    // selects and the distance expression tree are untouched (sacred).
    int q = t & 31, s = t >> 5;
    int n = n0 + q;
    const float* x1 = xyz1 + (size_t)b * 12288;
    float px = x1[n], py = x1[4096 + n], pz = x1[8192 + n];
    float s1 = px * px + py * py + pz * pz;
    float d0 = 1e30f, d1 = 1e30f, d2 = 1e30f;
    int i0 = 0, i1 = 0, i2 = 0;
    int j0 = s * 128;
    #pragma unroll 4
    for (int jj = 0; jj < 128; ++jj) {
        int j = j0 + jj;
        f32x4 v = cand[j];
        float dot = px * v[0] + py * v[1] + pz * v[2];
        float d = -2.0f * dot; d += s1; d += v[3];
        bool b0 = d < d0, b1 = d < d1, b2 = d < d2;
        i2 = b1 ? i1 : (b2 ? j : i2);
        i1 = b0 ? i0 : (b1 ? j : i1);
        i0 = b0 ? j : i0;
        d2 = __builtin_amdgcn_fmed3f(d, d1, d2);
        d1 = __builtin_amdgcn_fmed3f(d, d0, d1);
        d0 = fminf(d, d0);
    }
    mkd[q][s * 3 + 0] = d0; mki[q][s * 3 + 0] = i0;
    mkd[q][s * 3 + 1] = d1; mki[q][s * 3 + 1] = i1;
    mkd[q][s * 3 + 2] = d2; mki[q][s * 3 + 2] = i2;
    __syncthreads();   // (B) scans done -> cand dead, partials visible

    // p1 transpose into btile (aliases cand; safe after (B))
    #pragma unroll
    for (int j = 0; j < 4; ++j) {
        *(unsigned long long*)&btf[(n4 + j) * 136 + c4] = pack4bf(q0[j], q1[j], q2[j], q3[j]);
    }

    // merge 24 partials (t<32) in ascending split (=index) order;
    // strict < keeps the earlier (lower-index) entry on ties, matching top_k.
    if (t < 32) {
        float e0 = 1e30f, e1 = 1e30f, e2 = 1e30f;
        int a0 = 0, a1 = 0, a2 = 0;
        #pragma unroll
        for (int m = 0; m < 24; ++m) {
            float d = mkd[t][m]; int j = mki[t][m];
            bool b0 = d < e0, b1 = d < e1, b2 = d < e2;
            a2 = b1 ? a1 : (b2 ? j : a2);
            a1 = b0 ? a0 : (b1 ? j : a1);
            a0 = b0 ? j : a0;
            e2 = __builtin_amdgcn_fmed3f(d, e1, e2);
            e1 = __builtin_amdgcn_fmed3f(d, e0, e1);
            e0 = fminf(d, e0);
        }
        float dd0 = fmaxf(e0, 1e-10f), dd1 = fmaxf(e1, 1e-10f), dd2 = fmaxf(e2, 1e-10f);
        float w0 = 1.f / dd0, w1 = 1.f / dd1, w2 = 1.f / dd2;
        float swt = w0 + w1 + w2; w0 /= swt; w1 /= swt; w2 /= swt;
        sidx[t][0] = a0; sidx[t][1] = a1; sidx[t][2] = a2;
        sw[t][0] = w0; sw[t][1] = w1; sw[t][2] = w2;
    }
    __syncthreads();   // (C) btile + sidx/sw visible

    unsigned short* Xb = Xt + ((size_t)b * 4096 + n0) * 384;
    // Xt cols [0,128) from btile
    {
        int nn = t >> 3, cs = (t & 7) * 16;
        short8 v0 = *(const short8*)&btf[nn * 136 + cs];
        short8 v1 = *(const short8*)&btf[nn * 136 + cs + 8];
        unsigned short* dst = Xb + (size_t)nn * 384 + cs;
        *(short8*)dst = v0;
        *(short8*)(dst + 8) = v1;
    }
    // interpolation -> Xt cols [128,384); 8 lanes x 32 ch per point
    {
        int nn = t >> 3, cs = (t & 7) * 32;
        const unsigned short* pb = p2t + (size_t)b * 1024 * 256 + cs;
        const unsigned short* r0 = pb + (size_t)sidx[nn][0] * 256;
        const unsigned short* r1 = pb + (size_t)sidx[nn][1] * 256;
        const unsigned short* r2 = pb + (size_t)sidx[nn][2] * 256;
        float w0 = sw[nn][0], w1 = sw[nn][1], w2 = sw[nn][2];
        unsigned short* dst = Xb + (size_t)nn * 384 + 128 + cs;
        #pragma unroll
        for (int j = 0; j < 4; ++j) {
            short8 a = *(const short8*)(r0 + j * 8);
            short8 bb = *(const short8*)(r1 + j * 8);
            short8 cc = *(const short8*)(r2 + j * 8);
            short8 o;
            #pragma unroll
            for (int e = 0; e < 8; ++e) {
                float v = w0 * bf2f((unsigned short)a[e]) + w1 * bf2f((unsigned short)bb[e])
                        + w2 * bf2f((unsigned short)cc[e]);
                o[e] = (short)f2bf(v);
            }
            *(short8*)(dst + j * 8) = o;
        }
    }
}

// ---------- wide GEMM 128x256 with fused BN-stats epilogue ----------
// C[ar][bc] = sum_k A[ar][k]*B[bc][k], A,B row-major [rows][Kdim] bf16.
// out index = arow*sA + (brow>>12)*sBatch + (brow&4095)
// SMODE 1 (GEMM1): grid (Ablocks, 1);   ar0 = bx*128, br0 = 0.
//   partials per B-col over block's 128 A-rows: psp[bx*256 + col]
// SMODE 2 (GEMM2): grid (Bblocks, 2);   ar0 = by*128, br0 = bx*256.
//   partials per A-row over block's 256 B-rows: psp[bx*256 + ar0 + row]
template<int SMODE>
__global__ __launch_bounds__(256, 2) void k_gemm(const unsigned short* __restrict__ A,
        const unsigned short* __restrict__ B, unsigned short* __restrict__ C,
        int Kdim, size_t sA, size_t sBatch,
        float* __restrict__ psp, float* __restrict__ pqp) {
    __shared__ unsigned short lA[128 * 32];
    __shared__ unsigned short lB[256 * 32];
    __shared__ float sredS[4][128];
    __shared__ float sredQ[4][128];
    int t = threadIdx.x;
    int w = t >> 6, lane = t & 63;
    int ar0 = (SMODE == 1 ? blockIdx.x : blockIdx.y) * 128;
    int br0 = (SMODE == 1 ? blockIdx.y : blockIdx.x) * 256;
    int war = (w >> 1) * 64, wbr = (w & 1) * 128;
    f32x4 acc[4][8] = {};
    int rlo = lane & 15, khi = lane >> 4;
    for (int kk = 0; kk < Kdim; kk += 32) {
        #pragma unroll
        for (int it = 0; it < 2; ++it) {
            int qq = it * 256 + w * 64 + lane;
            int row = qq >> 2, kc = qq & 3;
            const unsigned short* srcA = A + (size_t)(ar0 + row) * Kdim + kk + ((kc ^ (row & 3)) << 3);
            gload_lds16(srcA, &lA[(size_t)(it * 256 + w * 64) * 8]);
        }
        #pragma unroll
        for (int it = 0; it < 4; ++it) {
            int qq = it * 256 + w * 64 + lane;
            int row = qq >> 2, kc = qq & 3;
            const unsigned short* srcB = B + (size_t)(br0 + row) * Kdim + kk + ((kc ^ (row & 3)) << 3);
            gload_lds16(srcB, &lB[(size_t)(it * 256 + w * 64) * 8]);
        }
        __syncthreads();
        short8 af[4], bfr[8];
        #pragma unroll
        for (int mi = 0; mi < 4; ++mi) {
            int r = war + mi * 16 + rlo;
            af[mi] = *(const short8*)&lA[(size_t)(r * 4 + (khi ^ (r & 3))) * 8];
        }
        #pragma unroll
        for (int ni = 0; ni < 8; ++ni) {
            int r = wbr + ni * 16 + rlo;
            bfr[ni] = *(const short8*)&lB[(size_t)(r * 4 + (khi ^ (r & 3))) * 8];
        }
        #pragma unroll
        for (int mi = 0; mi < 4; ++mi)
            #pragma unroll
            for (int ni = 0; ni < 8; ++ni)
                acc[mi][ni] = __builtin_amdgcn_mfma_f32_16x16x32_bf16(af[mi], bfr[ni], acc[mi][ni], 0, 0, 0);
        __syncthreads();
    }
    // C write
    #pragma unroll
    for (int mi = 0; mi < 4; ++mi) {
        #pragma unroll
        for (int ni = 0; ni < 8; ++ni) {
            #pragma unroll
            for (int r = 0; r < 4; ++r) {
                int arow = ar0 + war + mi * 16 + khi * 4 + r;
                int brow = br0 + wbr + ni * 16 + rlo;
                size_t oidx = (size_t)arow * sA + (size_t)(brow >> 12) * sBatch + (size_t)(brow & 4095);
                C[oidx] = f2bf(acc[mi][ni][r]);
            }
        }
    }
    // fused BN stats (f32 accumulators, deterministic per-block partials)
    if constexpr (SMODE == 1) {
        // per B-col sums over this block's 128 A-rows
        #pragma unroll
        for (int ni = 0; ni < 8; ++ni) {
            float s = 0.f, qs = 0.f;
            #pragma unroll
            for (int mi = 0; mi < 4; ++mi)
                #pragma unroll
                for (int r = 0; r < 4; ++r) { float v = acc[mi][ni][r]; s += v; qs += v * v; }
            s += __shfl_xor(s, 16); qs += __shfl_xor(qs, 16);
            s += __shfl_xor(s, 32); qs += __shfl_xor(qs, 32);
            if (khi == 0) { sredS[w][ni * 16 + rlo] = s; sredQ[w][ni * 16 + rlo] = qs; }
        }
        __syncthreads();
        {
            int c = t;  // 0..255
            float s, qs;
            if (c < 128) { s = sredS[0][c] + sredS[2][c]; qs = sredQ[0][c] + sredQ[2][c]; }
            else { s = sredS[1][c - 128] + sredS[3][c - 128]; qs = sredQ[1][c - 128] + sredQ[3][c - 128]; }
            size_t pi = (size_t)blockIdx.x * 256 + c;
            psp[pi] = s; pqp[pi] = qs;
        }
    } else {
        // per A-row sums over this block's 256 B-rows
        float rs[4][4], rq[4][4];
        #pragma unroll
        for (int mi = 0; mi < 4; ++mi) {
            #pragma unroll
            for (int r = 0; r < 4; ++r) {
                float s = 0.f, qs = 0.f;
                #pragma unroll
                for (int ni = 0; ni < 8; ++ni) { float v = acc[mi][ni][r]; s += v; qs += v * v; }
                s += __shfl_xor(s, 1); qs += __shfl_xor(qs, 1);
                s += __shfl_xor(s, 2); qs += __shfl_xor(qs, 2);
                s += __shfl_xor(s, 4); qs += __shfl_xor(qs, 4);
                s += __shfl_xor(s, 8); qs += __shfl_xor(qs, 8);
                rs[mi][r] = s; rq[mi][r] = qs;
            }
        }
        if (rlo == 0) {
            #pragma unroll
            for (int mi = 0; mi < 4; ++mi)
                #pragma unroll
                for (int r = 0; r < 4; ++r) {
                    sredS[w][mi * 16 + khi * 4 + r] = rs[mi][r];
                    sredQ[w][mi * 16 + khi * 4 + r] = rq[mi][r];
                }
        }
        __syncthreads();
        if (t < 128) {
            float s, qs;
            if (t < 64) { s = sredS[0][t] + sredS[1][t]; qs = sredQ[0][t] + sredQ[1][t]; }
            else { s = sredS[2][t - 64] + sredS[3][t - 64]; qs = sredQ[2][t - 64] + sredQ[3][t - 64]; }
            size_t pi = (size_t)blockIdx.x * 256 + ar0 + t;
            psp[pi] = s; pqp[pi] = qs;
        }
    }
}

// ---------- finalize BN coefficients: one block per channel, parallel over partials ----------
__global__ __launch_bounds__(256) void k_fin(const float* __restrict__ ps,
        const float* __restrict__ pq, const float* __restrict__ g,
        const float* __restrict__ be, float* __restrict__ av, float* __restrict__ bv,
        int npart) {
    int c = blockIdx.x;
    int t = threadIdx.x;
    float s = 0.f, q = 0.f;
    for (int i = t; i < npart; i += 256) {
        s += ps[(size_t)i * 256 + c];
        q += pq[(size_t)i * 256 + c];
    }
    #pragma unroll
    for (int off = 32; off; off >>= 1) { s += __shfl_down(s, off); q += __shfl_down(q, off); }
    __shared__ float ss[4], sq[4];
    if ((t & 63) == 0) { ss[t >> 6] = s; sq[t >> 6] = q; }
    __syncthreads();
    if (t == 0) {
        float S = ss[0] + ss[1] + ss[2] + ss[3];
        float Q = sq[0] + sq[1] + sq[2] + sq[3];
        float mean = S / 65536.0f;
        float var = Q / 65536.0f - mean * mean;
        float a = g[c] * rsqrtf(var + BN_EPS);
        av[c] = a; bv[c] = be[c] - mean * a;
    }
}

// ---------- normalize+relu h1 in place ----------
__global__ __launch_bounds__(256) void k_norm1(unsigned short* __restrict__ h1,
        const float* __restrict__ av, const float* __restrict__ bv) {
    size_t i0 = ((size_t)blockIdx.x * 256 + threadIdx.x) * 8;
    int c0 = (int)(i0 & 255);
    short8 v = *(short8*)&h1[i0];
    short8 o;
    #pragma unroll
    for (int j = 0; j < 8; ++j) {
        float x = bf2f((unsigned short)v[j]);
        float y = av[c0 + j] * x + bv[c0 + j];
        o[j] = (short)f2bf(fmaxf(y, 0.f));
    }
    *(short8*)&h1[i0] = o;
}

// ---------- final normalize+relu -> f32 out ----------
__global__ __launch_bounds__(256) void k_final(const unsigned short* __restrict__ h2,
        const float* __restrict__ av, const float* __restrict__ bv, float* __restrict__ out) {
    size_t i0 = ((size_t)blockIdx.x * 256 + threadIdx.x) * 8;
    int o = (int)((i0 >> 12) & 255);
    float a = av[o], b = bv[o];
    short8 v = *(const short8*)&h2[i0];
    f32x4 r0, r1;
    #pragma unroll
    for (int j = 0; j < 4; ++j) r0[j] = fmaxf(a * bf2f((unsigned short)v[j]) + b, 0.f);
    #pragma unroll
    for (int j = 0; j < 4; ++j) r1[j] = fmaxf(a * bf2f((unsigned short)v[4 + j]) + b, 0.f);
    *(f32x4*)&out[i0] = r0;
    *(f32x4*)&out[i0 + 4] = r1;
}

extern "C" void kernel_launch(void* const* d_in, const int* in_sizes, int n_in,
                              void* d_out, int out_size, void* d_ws, size_t ws_size,
                              hipStream_t stream) {
    const float* xyz1 = (const float*)d_in[0];
    const float* xyz2 = (const float*)d_in[1];
    const float* p1   = (const float*)d_in[2];
    const float* p2   = (const float*)d_in[3];
    const float* W1   = (const float*)d_in[4];
    const float* g1   = (const float*)d_in[5];
    const float* be1  = (const float*)d_in[6];
    const float* W2   = (const float*)d_in[7];
    const float* g2   = (const float*)d_in[8];
    const float* be2  = (const float*)d_in[9];
    float* out = (float*)d_out;
    char* ws = (char*)d_ws;

    unsigned short* Xt  = (unsigned short*)(ws);                    // 50,331,648 B
    unsigned short* h1  = (unsigned short*)(ws + 50331648);         // 33,554,432 B
    unsigned short* h2  = (unsigned short*)(ws + 83886080);         // 33,554,432 B
    // p2t shares h2's slot: dead before GEMM2 writes h2
    unsigned short* p2t = (unsigned short*)(ws + 83886080);         // 8,388,608 B
    unsigned short* W1b = (unsigned short*)(ws + 117440512);        // 196,608 B
    unsigned short* W2b = (unsigned short*)(ws + 117637120);        // 131,072 B
    float* ps1p = (float*)(ws + 117768192);                         // 524,288 B
    float* pq1p = (float*)(ws + 118292480);                         // 524,288 B
    float* ps2p = (float*)(ws + 118816768);                         // 524,288 B
    float* pq2p = (float*)(ws + 119341056);                         // 524,288 B
    float* a1v  = (float*)(ws + 119865344);
    float* b1v  = (float*)(ws + 119866368);
    float* a2v  = (float*)(ws + 119867392);
    float* b2v  = (float*)(ws + 119868416);

    k_convert<<<dim3(384), dim3(256), 0, stream>>>(W1, W2, W1b, W2b);
    k_tr_p2<<<dim3(64, 16), dim3(256), 0, stream>>>(p2, p2t);
    k_knnbuild<<<dim3(128, 16), dim3(256), 0, stream>>>(xyz1, xyz2, p1, p2t, Xt);
    // GEMM1: A = Xt (65536 x 384), B = W1b (256 x 384, full 256-tile) -> h1[n][o], + stats per o
    k_gemm<1><<<dim3(512, 1), dim3(256), 0, stream>>>(Xt, W1b, h1, 384, 256, 0, ps1p, pq1p);
    k_fin<<<dim3(256), dim3(256), 0, stream>>>(ps1p, pq1p, g1, be1, a1v, b1v, 512);
    k_norm1<<<dim3(8192), dim3(256), 0, stream>>>(h1, a1v, b1v);
    // GEMM2: A = W2b (256 x 256), B = h1n (65536 x 256) -> h2[b][o][n], + stats per o
    k_gemm<2><<<dim3(256, 2), dim3(256), 0, stream>>>(W2b, h1, h2, 256, 4096, 1048576, ps2p, pq2p);
    k_fin<<<dim3(256), dim3(256), 0, stream>>>(ps2p, pq2p, g2, be2, a2v, b2v, 256);
    k_final<<<dim3(8192), dim3(256), 0, stream>>>(h2, a2v, b2v, out);
}

// Round 11
// 133.872 us; speedup vs baseline: 2.4478x; 1.0368x over previous
//
#include <hip/hip_runtime.h>
#include <hip/hip_bf16.h>

typedef __attribute__((ext_vector_type(8))) short short8;
typedef __attribute__((ext_vector_type(4))) float f32x4;

#define BN_EPS 1e-5f

// ---------- bf16 helpers (RNE) ----------
__device__ __forceinline__ float bf2f(unsigned short u) {
    unsigned int x = ((unsigned int)u) << 16;
    union { unsigned int i; float f; } c; c.i = x; return c.f;
}
__device__ __forceinline__ unsigned short f2bf(float f) {
    union { float f; unsigned int i; } c; c.f = f;
    unsigned int lsb = (c.i >> 16) & 1u;
    c.i += 0x7fffu + lsb;
    return (unsigned short)(c.i >> 16);
}
__device__ __forceinline__ unsigned long long pack4bf(float a, float b, float c, float d) {
    unsigned long long r = (unsigned long long)f2bf(a)
        | ((unsigned long long)f2bf(b) << 16)
        | ((unsigned long long)f2bf(c) << 32)
        | ((unsigned long long)f2bf(d) << 48);
    return r;
}

// ---------- async global->LDS 16B ----------
typedef const unsigned int __attribute__((address_space(1)))* gas_t;
typedef unsigned int __attribute__((address_space(3)))* las_t;
__device__ __forceinline__ void gload_lds16(const void* src, void* ldsdst) {
    __builtin_amdgcn_global_load_lds((gas_t)src, (las_t)ldsdst, 16, 0, 0);
}

// ---------- transpose p2 [b][256][1024] f32 -> p2t [b][1024][256] bf16 ----------
// Also folds the W1/W2 bf16 conversion (one element per thread over the first
// 163840 global threads) — saves a separate launch.
__global__ __launch_bounds__(256) void k_tr_p2(const float* __restrict__ p2,
        unsigned short* __restrict__ p2t,
        const float* __restrict__ W1, const float* __restrict__ W2,
        unsigned short* __restrict__ W1b, unsigned short* __restrict__ W2b) {
    __shared__ unsigned short btile[32][136];
    int b = blockIdx.y;
    int n0 = (blockIdx.x & 31) * 32;
    int c0 = (blockIdx.x >> 5) * 128;
    int t = threadIdx.x;
    // fused weight conversion
    int gtid = (blockIdx.y * 64 + blockIdx.x) * 256 + t;
    if (gtid < 98304) W1b[gtid] = f2bf(W1[gtid]);
    else if (gtid < 163840) { int i = gtid - 98304; W2b[i] = f2bf(W2[i]); }

    const float* src = p2 + (size_t)b * 256 * 1024 + (size_t)c0 * 1024 + n0;
    int c4 = (t >> 3) * 4, n4 = (t & 7) * 4;
    f32x4 q0 = *(const f32x4*)&src[(size_t)(c4 + 0) * 1024 + n4];
    f32x4 q1 = *(const f32x4*)&src[(size_t)(c4 + 1) * 1024 + n4];
    f32x4 q2 = *(const f32x4*)&src[(size_t)(c4 + 2) * 1024 + n4];
    f32x4 q3 = *(const f32x4*)&src[(size_t)(c4 + 3) * 1024 + n4];
    #pragma unroll
    for (int j = 0; j < 4; ++j) {
        *(unsigned long long*)&btile[n4 + j][c4] = pack4bf(q0[j], q1[j], q2[j], q3[j]);
    }
    __syncthreads();
    int nn = t >> 3, cs = (t & 7) * 16;
    short8 v0 = *(const short8*)&btile[nn][cs];
    short8 v1 = *(const short8*)&btile[nn][cs + 8];
    unsigned short* dst = p2t + ((size_t)b * 1024 + n0 + nn) * 256 + c0 + cs;
    *(short8*)dst = v0;
    *(short8*)(dst + 8) = v1;
}

// ---------- fused 3-NN + build: Xt[b*4096+n][384] = concat(points1^T, interp) ----------
// LDS 21760 B -> 7 blocks/CU. btile aliases cand (dead after scan).
__global__ __launch_bounds__(256) void k_knnbuild(const float* __restrict__ xyz1,
        const float* __restrict__ xyz2, const float* __restrict__ p1,
        const unsigned short* __restrict__ p2t, unsigned short* __restrict__ Xt) {
    __shared__ f32x4 cand[1024];            // (x, y, z, |p|^2); later aliased as btile
    __shared__ float mkd[32][24];           // 24 partial dists per query
    __shared__ unsigned short mki[32][24];  // 24 partial indices per query
    __shared__ int sidx[32][3];
    __shared__ float sw[32][3];
    unsigned short* btf = (unsigned short*)cand;   // btile alias: btf[r*136 + c]
    int b = blockIdx.y;
    int n0 = blockIdx.x * 32;
    int t = threadIdx.x;

    // issue p1 loads early: they complete under the VALU-bound scan
    const float* p1b = p1 + (size_t)b * 128 * 4096 + n0;
    int c4 = (t >> 3) * 4, n4 = (t & 7) * 4;
    f32x4 q0 = *(const f32x4*)&p1b[(size_t)(c4 + 0) * 4096 + n4];
    f32x4 q1 = *(const f32x4*)&p1b[(size_t)(c4 + 1) * 4096 + n4];
    f32x4 q2 = *(const f32x4*)&p1b[(size_t)(c4 + 2) * 4096 + n4];
    f32x4 q3 = *(const f32x4*)&p1b[(size_t)(c4 + 3) * 4096 + n4];

    const float* x2 = xyz2 + (size_t)b * 3072;
    for (int i = t; i < 1024; i += 256) {
        float x = x2[i], y = x2[1024 + i], z = x2[2048 + i];
        f32x4 v;
        v[0] = x; v[1] = y; v[2] = z; v[3] = x * x + y * y + z * z;
        cand[i] = v;
    }
    __syncthreads();   // (A) cand ready

    // scan: 8 splits x 128 candidates; exact-f32 branchless top-3.
    // Distance expression tree is byte-identical to the proven version (sacred).
    int q = t & 31, s = t >> 5;
    int n = n0 + q;
    const float* x1 = xyz1 + (size_t)b * 12288;
    float px = x1[n], py = x1[4096 + n], pz = x1[8192 + n];
    float s1 = px * px + py * py + pz * pz;
    float d0 = 1e30f, d1 = 1e30f, d2 = 1e30f;
    int i0 = 0, i1 = 0, i2 = 0;
    int j0 = s * 128;
    #pragma unroll 4
    for (int jj = 0; jj < 128; ++jj) {
        int j = j0 + jj;
        f32x4 v = cand[j];
        float dot = px * v[0] + py * v[1] + pz * v[2];
        float d = -2.0f * dot; d += s1; d += v[3];
        bool b0 = d < d0, b1 = d < d1, b2 = d < d2;
        i2 = b1 ? i1 : (b2 ? j : i2);
        i1 = b0 ? i0 : (b1 ? j : i1);
        i0 = b0 ? j : i0;
        d2 = __builtin_amdgcn_fmed3f(d, d1, d2);
        d1 = __builtin_amdgcn_fmed3f(d, d0, d1);
        d0 = fminf(d, d0);
    }
    mkd[q][s * 3 + 0] = d0; mki[q][s * 3 + 0] = (unsigned short)i0;
    mkd[q][s * 3 + 1] = d1; mki[q][s * 3 + 1] = (unsigned short)i1;
    mkd[q][s * 3 + 2] = d2; mki[q][s * 3 + 2] = (unsigned short)i2;
    __syncthreads();   // (B) scans done -> cand dead, partials visible

    // p1 transpose into btile (aliases cand; safe after (B))
    #pragma unroll
    for (int j = 0; j < 4; ++j) {
        *(unsigned long long*)&btf[(n4 + j) * 136 + c4] = pack4bf(q0[j], q1[j], q2[j], q3[j]);
    }

    // merge 24 partials (t<32) in ascending split (=index) order;
    // strict < keeps the earlier (lower-index) entry on ties, matching top_k.
    if (t < 32) {
        float e0 = 1e30f, e1 = 1e30f, e2 = 1e30f;
        int a0 = 0, a1 = 0, a2 = 0;
        #pragma unroll
        for (int m = 0; m < 24; ++m) {
            float d = mkd[t][m]; int j = (int)mki[t][m];
            bool b0 = d < e0, b1 = d < e1, b2 = d < e2;
            a2 = b1 ? a1 : (b2 ? j : a2);
            a1 = b0 ? a0 : (b1 ? j : a1);
            a0 = b0 ? j : a0;
            e2 = __builtin_amdgcn_fmed3f(d, e1, e2);
            e1 = __builtin_amdgcn_fmed3f(d, e0, e1);
            e0 = fminf(d, e0);
        }
        float dd0 = fmaxf(e0, 1e-10f), dd1 = fmaxf(e1, 1e-10f), dd2 = fmaxf(e2, 1e-10f);
        float w0 = 1.f / dd0, w1 = 1.f / dd1, w2 = 1.f / dd2;
        float swt = w0 + w1 + w2; w0 /= swt; w1 /= swt; w2 /= swt;
        sidx[t][0] = a0; sidx[t][1] = a1; sidx[t][2] = a2;
        sw[t][0] = w0; sw[t][1] = w1; sw[t][2] = w2;
    }
    __syncthreads();   // (C) btile + sidx/sw visible

    unsigned short* Xb = Xt + ((size_t)b * 4096 + n0) * 384;
    // Xt cols [0,128) from btile
    {
        int nn = t >> 3, cs = (t & 7) * 16;
        short8 v0 = *(const short8*)&btf[nn * 136 + cs];
        short8 v1 = *(const short8*)&btf[nn * 136 + cs + 8];
        unsigned short* dst = Xb + (size_t)nn * 384 + cs;
        *(short8*)dst = v0;
        *(short8*)(dst + 8) = v1;
    }
    // interpolation -> Xt cols [128,384); 8 lanes x 32 ch per point
    {
        int nn = t >> 3, cs = (t & 7) * 32;
        const unsigned short* pb = p2t + (size_t)b * 1024 * 256 + cs;
        const unsigned short* r0 = pb + (size_t)sidx[nn][0] * 256;
        const unsigned short* r1 = pb + (size_t)sidx[nn][1] * 256;
        const unsigned short* r2 = pb + (size_t)sidx[nn][2] * 256;
        float w0 = sw[nn][0], w1 = sw[nn][1], w2 = sw[nn][2];
        unsigned short* dst = Xb + (size_t)nn * 384 + 128 + cs;
        #pragma unroll
        for (int j = 0; j < 4; ++j) {
            short8 a = *(const short8*)(r0 + j * 8);
            short8 bb = *(const short8*)(r1 + j * 8);
            short8 cc = *(const short8*)(r2 + j * 8);
            short8 o;
            #pragma unroll
            for (int e = 0; e < 8; ++e) {
                float v = w0 * bf2f((unsigned short)a[e]) + w1 * bf2f((unsigned short)bb[e])
                        + w2 * bf2f((unsigned short)cc[e]);
                o[e] = (short)f2bf(v);
            }
            *(short8*)(dst + j * 8) = o;
        }
    }
}

// ---------- wide GEMM 128x256 with fused BN-stats epilogue ----------
// C[ar][bc] = sum_k A[ar][k]*B[bc][k], A,B row-major [rows][Kdim] bf16.
// out index = arow*sA + (brow>>12)*sBatch + (brow&4095)
// SMODE 1 (GEMM1): grid (Ablocks, 1);   ar0 = bx*128, br0 = 0.
//   partials per B-col over block's 128 A-rows: psp[bx*256 + col]
// SMODE 2 (GEMM2): grid (Bblocks, 2);   ar0 = by*128, br0 = bx*256.
//   partials per A-row over block's 256 B-rows: psp[bx*256 + ar0 + row]
template<int SMODE>
__global__ __launch_bounds__(256, 2) void k_gemm(const unsigned short* __restrict__ A,
        const unsigned short* __restrict__ B, unsigned short* __restrict__ C,
        int Kdim, size_t sA, size_t sBatch,
        float* __restrict__ psp, float* __restrict__ pqp) {
    __shared__ unsigned short lA[128 * 32];
    __shared__ unsigned short lB[256 * 32];
    __shared__ float sredS[4][128];
    __shared__ float sredQ[4][128];
    int t = threadIdx.x;
    int w = t >> 6, lane = t & 63;
    int ar0 = (SMODE == 1 ? blockIdx.x : blockIdx.y) * 128;
    int br0 = (SMODE == 1 ? blockIdx.y : blockIdx.x) * 256;
    int war = (w >> 1) * 64, wbr = (w & 1) * 128;
    f32x4 acc[4][8] = {};
    int rlo = lane & 15, khi = lane >> 4;
    for (int kk = 0; kk < Kdim; kk += 32) {
        #pragma unroll
        for (int it = 0; it < 2; ++it) {
            int qq = it * 256 + w * 64 + lane;
            int row = qq >> 2, kc = qq & 3;
            const unsigned short* srcA = A + (size_t)(ar0 + row) * Kdim + kk + ((kc ^ (row & 3)) << 3);
            gload_lds16(srcA, &lA[(size_t)(it * 256 + w * 64) * 8]);
        }
        #pragma unroll
        for (int it = 0; it < 4; ++it) {
            int qq = it * 256 + w * 64 + lane;
            int row = qq >> 2, kc = qq & 3;
            const unsigned short* srcB = B + (size_t)(br0 + row) * Kdim + kk + ((kc ^ (row & 3)) << 3);
            gload_lds16(srcB, &lB[(size_t)(it * 256 + w * 64) * 8]);
        }
        __syncthreads();
        short8 af[4], bfr[8];
        #pragma unroll
        for (int mi = 0; mi < 4; ++mi) {
            int r = war + mi * 16 + rlo;
            af[mi] = *(const short8*)&lA[(size_t)(r * 4 + (khi ^ (r & 3))) * 8];
        }
        #pragma unroll
        for (int ni = 0; ni < 8; ++ni) {
            int r = wbr + ni * 16 + rlo;
            bfr[ni] = *(const short8*)&lB[(size_t)(r * 4 + (khi ^ (r & 3))) * 8];
        }
        #pragma unroll
        for (int mi = 0; mi < 4; ++mi)
            #pragma unroll
            for (int ni = 0; ni < 8; ++ni)
                acc[mi][ni] = __builtin_amdgcn_mfma_f32_16x16x32_bf16(af[mi], bfr[ni], acc[mi][ni], 0, 0, 0);
        __syncthreads();
    }
    // C write
    #pragma unroll
    for (int mi = 0; mi < 4; ++mi) {
        #pragma unroll
        for (int ni = 0; ni < 8; ++ni) {
            #pragma unroll
            for (int r = 0; r < 4; ++r) {
                int arow = ar0 + war + mi * 16 + khi * 4 + r;
                int brow = br0 + wbr + ni * 16 + rlo;
                size_t oidx = (size_t)arow * sA + (size_t)(brow >> 12) * sBatch + (size_t)(brow & 4095);
                C[oidx] = f2bf(acc[mi][ni][r]);
            }
        }
    }
    // fused BN stats (f32 accumulators, deterministic per-block partials)
    if constexpr (SMODE == 1) {
        #pragma unroll
        for (int ni = 0; ni < 8; ++ni) {
            float s = 0.f, qs = 0.f;
            #pragma unroll
            for (int mi = 0; mi < 4; ++mi)
                #pragma unroll
                for (int r = 0; r < 4; ++r) { float v = acc[mi][ni][r]; s += v; qs += v * v; }
            s += __shfl_xor(s, 16); qs += __shfl_xor(qs, 16);
            s += __shfl_xor(s, 32); qs += __shfl_xor(qs, 32);
            if (khi == 0) { sredS[w][ni * 16 + rlo] = s; sredQ[w][ni * 16 + rlo] = qs; }
        }
        __syncthreads();
        {
            int c = t;  // 0..255
            float s, qs;
            if (c < 128) { s = sredS[0][c] + sredS[2][c]; qs = sredQ[0][c] + sredQ[2][c]; }
            else { s = sredS[1][c - 128] + sredS[3][c - 128]; qs = sredQ[1][c - 128] + sredQ[3][c - 128]; }
            size_t pi = (size_t)blockIdx.x * 256 + c;
            psp[pi] = s; pqp[pi] = qs;
        }
    } else {
        float rs[4][4], rq[4][4];
        #pragma unroll
        for (int mi = 0; mi < 4; ++mi) {
            #pragma unroll
            for (int r = 0; r < 4; ++r) {
                float s = 0.f, qs = 0.f;
                #pragma unroll
                for (int ni = 0; ni < 8; ++ni) { float v = acc[mi][ni][r]; s += v; qs += v * v; }
                s += __shfl_xor(s, 1); qs += __shfl_xor(qs, 1);
                s += __shfl_xor(s, 2); qs += __shfl_xor(qs, 2);
                s += __shfl_xor(s, 4); qs += __shfl_xor(qs, 4);
                s += __shfl_xor(s, 8); qs += __shfl_xor(qs, 8);
                rs[mi][r] = s; rq[mi][r] = qs;
            }
        }
        if (rlo == 0) {
            #pragma unroll
            for (int mi = 0; mi < 4; ++mi)
                #pragma unroll
                for (int r = 0; r < 4; ++r) {
                    sredS[w][mi * 16 + khi * 4 + r] = rs[mi][r];
                    sredQ[w][mi * 16 + khi * 4 + r] = rq[mi][r];
                }
        }
        __syncthreads();
        if (t < 128) {
            float s, qs;
            if (t < 64) { s = sredS[0][t] + sredS[1][t]; qs = sredQ[0][t] + sredQ[1][t]; }
            else { s = sredS[2][t - 64] + sredS[3][t - 64]; qs = sredQ[2][t - 64] + sredQ[3][t - 64]; }
            size_t pi = (size_t)blockIdx.x * 256 + ar0 + t;
            psp[pi] = s; pqp[pi] = qs;
        }
    }
}

// ---------- finalize BN coefficients: one block per channel, parallel over partials ----------
__global__ __launch_bounds__(256) void k_fin(const float* __restrict__ ps,
        const float* __restrict__ pq, const float* __restrict__ g,
        const float* __restrict__ be, float* __restrict__ av, float* __restrict__ bv,
        int npart) {
    int c = blockIdx.x;
    int t = threadIdx.x;
    float s = 0.f, q = 0.f;
    for (int i = t; i < npart; i += 256) {
        s += ps[(size_t)i * 256 + c];
        q += pq[(size_t)i * 256 + c];
    }
    #pragma unroll
    for (int off = 32; off; off >>= 1) { s += __shfl_down(s, off); q += __shfl_down(q, off); }
    __shared__ float ss[4], sq[4];
    if ((t & 63) == 0) { ss[t >> 6] = s; sq[t >> 6] = q; }
    __syncthreads();
    if (t == 0) {
        float S = ss[0] + ss[1] + ss[2] + ss[3];
        float Q = sq[0] + sq[1] + sq[2] + sq[3];
        float mean = S / 65536.0f;
        float var = Q / 65536.0f - mean * mean;
        float a = g[c] * rsqrtf(var + BN_EPS);
        av[c] = a; bv[c] = be[c] - mean * a;
    }
}

// ---------- normalize+relu h1 in place ----------
__global__ __launch_bounds__(256) void k_norm1(unsigned short* __restrict__ h1,
        const float* __restrict__ av, const float* __restrict__ bv) {
    size_t i0 = ((size_t)blockIdx.x * 256 + threadIdx.x) * 8;
    int c0 = (int)(i0 & 255);
    short8 v = *(short8*)&h1[i0];
    short8 o;
    #pragma unroll
    for (int j = 0; j < 8; ++j) {
        float x = bf2f((unsigned short)v[j]);
        float y = av[c0 + j] * x + bv[c0 + j];
        o[j] = (short)f2bf(fmaxf(y, 0.f));
    }
    *(short8*)&h1[i0] = o;
}

// ---------- final normalize+relu -> f32 out ----------
__global__ __launch_bounds__(256) void k_final(const unsigned short* __restrict__ h2,
        const float* __restrict__ av, const float* __restrict__ bv, float* __restrict__ out) {
    size_t i0 = ((size_t)blockIdx.x * 256 + threadIdx.x) * 8;
    int o = (int)((i0 >> 12) & 255);
    float a = av[o], b = bv[o];
    short8 v = *(const short8*)&h2[i0];
    f32x4 r0, r1;
    #pragma unroll
    for (int j = 0; j < 4; ++j) r0[j] = fmaxf(a * bf2f((unsigned short)v[j]) + b, 0.f);
    #pragma unroll
    for (int j = 0; j < 4; ++j) r1[j] = fmaxf(a * bf2f((unsigned short)v[4 + j]) + b, 0.f);
    *(f32x4*)&out[i0] = r0;
    *(f32x4*)&out[i0 + 4] = r1;
}

extern "C" void kernel_launch(void* const* d_in, const int* in_sizes, int n_in,
                              void* d_out, int out_size, void* d_ws, size_t ws_size,
                              hipStream_t stream) {
    const float* xyz1 = (const float*)d_in[0];
    const float* xyz2 = (const float*)d_in[1];
    const float* p1   = (const float*)d_in[2];
    const float* p2   = (const float*)d_in[3];
    const float* W1   = (const float*)d_in[4];
    const float* g1   = (const float*)d_in[5];
    const float* be1  = (const float*)d_in[6];
    const float* W2   = (const float*)d_in[7];
    const float* g2   = (const float*)d_in[8];
    const float* be2  = (const float*)d_in[9];
    float* out = (float*)d_out;
    char* ws = (char*)d_ws;

    unsigned short* Xt  = (unsigned short*)(ws);                    // 50,331,648 B
    unsigned short* h1  = (unsigned short*)(ws + 50331648);         // 33,554,432 B
    unsigned short* h2  = (unsigned short*)(ws + 83886080);         // 33,554,432 B
    // p2t shares h2's slot: dead before GEMM2 writes h2
    unsigned short* p2t = (unsigned short*)(ws + 83886080);         // 8,388,608 B
    unsigned short* W1b = (unsigned short*)(ws + 117440512);        // 196,608 B
    unsigned short* W2b = (unsigned short*)(ws + 117637120);        // 131,072 B
    float* ps1p = (float*)(ws + 117768192);                         // 524,288 B
    float* pq1p = (float*)(ws + 118292480);                         // 524,288 B
    float* ps2p = (float*)(ws + 118816768);                         // 524,288 B
    float* pq2p = (float*)(ws + 119341056);                         // 524,288 B
    float* a1v  = (float*)(ws + 119865344);
    float* b1v  = (float*)(ws + 119866368);
    float* a2v  = (float*)(ws + 119867392);
    float* b2v  = (float*)(ws + 119868416);

    k_tr_p2<<<dim3(64, 16), dim3(256), 0, stream>>>(p2, p2t, W1, W2, W1b, W2b);
    k_knnbuild<<<dim3(128, 16), dim3(256), 0, stream>>>(xyz1, xyz2, p1, p2t, Xt);
    // GEMM1: A = Xt (65536 x 384), B = W1b (256 x 384, full 256-tile) -> h1[n][o], + stats per o
    k_gemm<1><<<dim3(512, 1), dim3(256), 0, stream>>>(Xt, W1b, h1, 384, 256, 0, ps1p, pq1p);
    k_fin<<<dim3(256), dim3(256), 0, stream>>>(ps1p, pq1p, g1, be1, a1v, b1v, 512);
    k_norm1<<<dim3(8192), dim3(256), 0, stream>>>(h1, a1v, b1v);
    // GEMM2: A = W2b (256 x 256), B = h1n (65536 x 256) -> h2[b][o][n], + stats per o
    k_gemm<2><<<dim3(256, 2), dim3(256), 0, stream>>>(W2b, h1, h2, 256, 4096, 1048576, ps2p, pq2p);
    k_fin<<<dim3(256), dim3(256), 0, stream>>>(ps2p, pq2p, g2, be2, a2v, b2v, 256);
    k_final<<<dim3(8192), dim3(256), 0, stream>>>(h2, a2v, b2v, out);
}